// Round 17
// baseline (1297.448 us; speedup 1.0000x reference)
//
#include <hip/hip_runtime.h>
#include <hip/hip_bf16.h>

// RNN_80848464380442: B=64, S=2048, V=50257, E=128, H=256, C=2 (f32 in/out, x int32)
// Stage 1: xw[tok][sig(j)] = bU[j] + sum_e emb[x]*W  (fp16 to ws, sigma-permuted cols)
// Stage 2: MFMA scan, 16 blocks x 4 batch rows, 4 waves x 4 N-tiles (256 thr).
//          R16 base (zero bank conflicts) + CHUNKED BURST xw prefetch: 8 steps of xw
//          loaded into registers per burst (ping-pong Xc/Xn, full unroll -> static
//          indexing), so 7 of 8 __syncthreads have no outstanding vmem -> the
//          vmcnt(0) barrier drain (~400 cyc/step, the R14/R16 unexplained term)
//          amortizes to ~15 cyc/step. Plus 4-deep split MFMA chains (latency exposed
//          at 1 wave/SIMD). D slot q == batch row q -> lane owns row kg.
// Stage 3: logits + h output post-loop from LDS.
// sigma: j = 64w+16s+n  ->  p = 64w+4n+s

#define HB 256
#define EB 128
#define SB 2048
#define BB 64
#define TPB 32
#define ROWS 4
#define PITCH 272   // u16/row = 544 B; <=2-way on A-reads (free); R16-verified 0 conflicts
#define CHUNK 8

typedef unsigned short u16;
typedef __attribute__((ext_vector_type(4))) float f32x4;
typedef __attribute__((ext_vector_type(8))) _Float16 f16x8;
typedef __attribute__((ext_vector_type(2))) __fp16 fp16x2_t;

__device__ __forceinline__ u16 f2h_bits(float f) {
    union { _Float16 h; u16 b; } x; x.h = (_Float16)f; return x.b;
}
__device__ __forceinline__ float h2f_bits(u16 b) {
    union { u16 b; _Float16 h; } x; x.b = b; return (float)x.h;
}
__device__ __forceinline__ float tanh_fast(float z) {
    float E = exp2f(z * 2.885390082f);             // e^(2z); tanh = 1 - 2/(e^2z + 1)
    return fmaf(-2.f, __builtin_amdgcn_rcpf(E + 1.f), 1.f);
}
__device__ __forceinline__ unsigned pkrtz(float a, float b) {
    fp16x2_t p = __builtin_amdgcn_cvt_pkrtz(a, b);
    return __builtin_bit_cast(unsigned, p);
}
__device__ __forceinline__ float sel4(f32x4 v, int kg) {   // v[kg] via cndmask chain
    float r = v[0];
    r = (kg == 1) ? v[1] : r;
    r = (kg == 2) ? v[2] : r;
    r = (kg == 3) ? v[3] : r;
    return r;
}

__device__ __forceinline__ int sig(int j)    { return (j & 0xC0) | ((j & 15) << 2) | ((j >> 4) & 3); }
__device__ __forceinline__ int invsig(int p) { return (p & 0xC0) | ((p & 3) << 4) | ((p >> 2) & 15); }

// ---------------- Stage 1: embed + project (32 tokens per 256-thread block) --------
__global__ __launch_bounds__(256) void embed_proj(
    const int* __restrict__ x, const float* __restrict__ emb,
    const float* __restrict__ W, const float* __restrict__ bU,
    u16* __restrict__ xw)
{
    __shared__ __align__(16) float el[TPB][EB];   // 16 KB
    __shared__ int toks[TPB];

    const int tid = threadIdx.x;
    const long base = (long)blockIdx.x * TPB;

    if (tid < TPB) toks[tid] = x[base + tid];
    __syncthreads();

    for (int r = 0; r < TPB * EB / 256; ++r) {
        int i = tid + r * 256;
        int row = i >> 7, e = i & (EB - 1);
        int u = toks[row];
        el[row][e] = (u == 0) ? 0.f : emb[(size_t)u * EB + e];   // padding_idx=0
    }
    __syncthreads();

    const int j = tid;
    const int sj = sig(j);
    const float bu = bU[j];
    float acc[TPB];
    #pragma unroll
    for (int t = 0; t < TPB; ++t) acc[t] = bu;

    for (int e0 = 0; e0 < EB; e0 += 4) {
        float w0 = W[(e0 + 0) * HB + j];
        float w1 = W[(e0 + 1) * HB + j];
        float w2 = W[(e0 + 2) * HB + j];
        float w3 = W[(e0 + 3) * HB + j];
        #pragma unroll
        for (int t = 0; t < TPB; ++t) {
            float4 ev = *(const float4*)&el[t][e0];
            acc[t] = fmaf(ev.x, w0, acc[t]);
            acc[t] = fmaf(ev.y, w1, acc[t]);
            acc[t] = fmaf(ev.z, w2, acc[t]);
            acc[t] = fmaf(ev.w, w3, acc[t]);
        }
    }
    #pragma unroll
    for (int t = 0; t < TPB; ++t)
        xw[(base + t) * HB + sj] = f2h_bits(acc[t]);
}

// ---------------- Stage 2+3: MFMA scan, 16 blocks x 256 threads (4 waves) ----------
// STEP_B(PAR, X): one scan step; PAR = compile-time buffer parity; X = this step's
// xw uint2 (register). Split 4-deep MFMA chains; 4 tanh; one b64 write; barrier.
#define STEP_B(PAR, X)                                                             \
  {                                                                                \
    float xv0 = h2f_bits((u16)(X.x & 0xffffu));                                    \
    float xv1 = h2f_bits((u16)(X.x >> 16));                                        \
    float xv2 = h2f_bits((u16)(X.y & 0xffffu));                                    \
    float xv3 = h2f_bits((u16)(X.y >> 16));                                        \
    f32x4 aA = {xv0, xv0, xv0, xv0}, aB = {xv1, xv1, xv1, xv1};                    \
    f32x4 aC = {xv2, xv2, xv2, xv2}, aD = {xv3, xv3, xv3, xv3};                    \
    f32x4 bA = {0.f,0.f,0.f,0.f}, bB = {0.f,0.f,0.f,0.f};                          \
    f32x4 bC = {0.f,0.f,0.f,0.f}, bD = {0.f,0.f,0.f,0.f};                          \
    f16x8 Af[8];                                                                   \
    _Pragma("unroll")                                                              \
    for (int ks = 0; ks < 8; ++ks) {                                               \
        uint4 av = *(const uint4*)&H[PAR][n & 3][ks * 32 + kg * 8];                \
        Af[ks] = __builtin_bit_cast(f16x8, av);                                    \
    }                                                                              \
    _Pragma("unroll")                                                              \
    for (int ks = 0; ks < 4; ++ks) {                                               \
        aA = __builtin_amdgcn_mfma_f32_16x16x32_f16(Af[ks], Bf[0][ks], aA, 0, 0, 0);       \
        aB = __builtin_amdgcn_mfma_f32_16x16x32_f16(Af[ks], Bf[1][ks], aB, 0, 0, 0);       \
        aC = __builtin_amdgcn_mfma_f32_16x16x32_f16(Af[ks], Bf[2][ks], aC, 0, 0, 0);       \
        aD = __builtin_amdgcn_mfma_f32_16x16x32_f16(Af[ks], Bf[3][ks], aD, 0, 0, 0);       \
        bA = __builtin_amdgcn_mfma_f32_16x16x32_f16(Af[ks + 4], Bf[0][ks + 4], bA, 0, 0, 0); \
        bB = __builtin_amdgcn_mfma_f32_16x16x32_f16(Af[ks + 4], Bf[1][ks + 4], bB, 0, 0, 0); \
        bC = __builtin_amdgcn_mfma_f32_16x16x32_f16(Af[ks + 4], Bf[2][ks + 4], bC, 0, 0, 0); \
        bD = __builtin_amdgcn_mfma_f32_16x16x32_f16(Af[ks + 4], Bf[3][ks + 4], bD, 0, 0, 0); \
    }                                                                              \
    aA += bA; aB += bB; aC += bC; aD += bD;                                        \
    {                                                                              \
        float t0 = tanh_fast(sel4(aA, kg));                                        \
        float t1 = tanh_fast(sel4(aB, kg));                                        \
        float t2 = tanh_fast(sel4(aC, kg));                                        \
        float t3 = tanh_fast(sel4(aD, kg));                                        \
        *(uint2*)&H[PAR ^ 1][kg][pbase] = make_uint2(pkrtz(t0, t1), pkrtz(t2, t3)); \
    }                                                                              \
    __syncthreads();                                                               \
  }

// Issue CHUNK xw loads for steps T0..T0+CHUNK-1 into register array X (static idx).
#define BURST(X, T0)                                                               \
  _Pragma("unroll")                                                                \
  for (int k = 0; k < CHUNK; ++k) {                                                \
      int tt = (T0) + k;                                                           \
      tt = tt < SB ? tt : SB - 1;                                                  \
      X[k] = *(const uint2*)&xw[gb + (unsigned)tt * HB];                           \
  }

__global__ __launch_bounds__(256, 1) void rnn_scan_mfma(
    const u16* __restrict__ xw, const float* __restrict__ U,
    const float* __restrict__ V, const float* __restrict__ bV,
    float* __restrict__ out)
{
    __shared__ __align__(16) u16 H[2][ROWS][PITCH];   // double-buffered h (fp16), sigma order

    const int tid  = threadIdx.x;
    const int lane = tid & 63;
    const int w    = tid >> 6;            // wave 0..3, owns N-tiles 4w..4w+3
    const int b0   = blockIdx.x * ROWS;

    {   // zero both H buffers (incl. pad)
        unsigned* hz = (unsigned*)H;
        for (int i = tid; i < 2 * ROWS * PITCH / 2; i += 256) hz[i] = 0u;
    }

    const int n  = lane & 15;             // A-m / B-n / D-col
    const int kg = lane >> 4;             // 0..3; lane owns batch row kg

    // ---- B-frag preload via sigma^-1: Bf[s][ks], tile nt=4w+s, col j_out=nt*16+n ----
    f16x8 Bf[4][8];
    #pragma unroll
    for (int s = 0; s < 4; ++s) {
        const int col = (4 * w + s) * 16 + n;
        #pragma unroll
        for (int ks = 0; ks < 8; ++ks) {
            union { f16x8 v; u16 h[8]; } tmp;
            #pragma unroll
            for (int e = 0; e < 8; ++e) {
                const int p = ks * 32 + kg * 8 + e;          // storage k
                const int jin = invsig(p);                   // actual contraction j
                tmp.h[e] = f2h_bits(U[(size_t)jin * HB + col]);
            }
            Bf[s][ks] = tmp.v;
        }
    }

    // ---- per-lane mapping: row kg, sigma col base pbase = 64w+4n (tiles s=0..3) ----
    const int pbase = 64 * w + 4 * n;
    const unsigned gb = ((unsigned)(b0 + kg) * SB) * HB + pbase;

    uint2 Xc[CHUNK], Xn[CHUNK];
    BURST(Xc, 0);
    BURST(Xn, CHUNK);
    __syncthreads();

    for (int t = 0; t < SB; t += 2 * CHUNK) {
        STEP_B(0, Xc[0]); STEP_B(1, Xc[1]); STEP_B(0, Xc[2]); STEP_B(1, Xc[3]);
        STEP_B(0, Xc[4]); STEP_B(1, Xc[5]); STEP_B(0, Xc[6]); STEP_B(1, Xc[7]);
        BURST(Xc, t + 2 * CHUNK);          // issued after a barrier; drains next barrier
        STEP_B(0, Xn[0]); STEP_B(1, Xn[1]); STEP_B(0, Xn[2]); STEP_B(1, Xn[3]);
        STEP_B(0, Xn[4]); STEP_B(1, Xn[5]); STEP_B(0, Xn[6]); STEP_B(1, Xn[7]);
        BURST(Xn, t + 3 * CHUNK);
    }

    // h output (f32 from fp16 H[0]; SB even -> final h in buffer 0)
    for (int i = tid; i < ROWS * HB; i += 256) {
        const int r = i >> 8, p = i & 255;
        out[BB * 2 + (size_t)(b0 + r) * HB + invsig(p)] = h2f_bits(H[0][r][p]);
    }

    // logits: first 64 threads = 4 rows x 16 partials
    if (tid < ROWS * 16) {
        const int r = tid >> 4, part = tid & 15;
        float s0 = 0.f, s1 = 0.f;
        #pragma unroll
        for (int i = 0; i < 16; ++i) {
            const int p = part * 16 + i;
            const int j = invsig(p);
            float hh = h2f_bits(H[0][r][p]);
            s0 = fmaf(hh, V[j * 2 + 0], s0);
            s1 = fmaf(hh, V[j * 2 + 1], s1);
        }
        #pragma unroll
        for (int o = 8; o > 0; o >>= 1) {
            s0 += __shfl_down(s0, o, 16);
            s1 += __shfl_down(s1, o, 16);
        }
        if (part == 0) {
            out[(size_t)(b0 + r) * 2 + 0] = s0 + bV[0];
            out[(size_t)(b0 + r) * 2 + 1] = s1 + bV[1];
        }
    }
}

extern "C" void kernel_launch(void* const* d_in, const int* in_sizes, int n_in,
                              void* d_out, int out_size, void* d_ws, size_t ws_size,
                              hipStream_t stream) {
    const int*   x   = (const int*)d_in[0];
    const float* emb = (const float*)d_in[1];
    const float* W   = (const float*)d_in[2];
    const float* U   = (const float*)d_in[3];
    const float* bU  = (const float*)d_in[4];
    const float* V   = (const float*)d_in[5];
    const float* bV  = (const float*)d_in[6];
    float* out = (float*)d_out;
    u16*   xw  = (u16*)d_ws;   // 64 MiB fp16 scratch, sigma-permuted columns

    embed_proj<<<BB * SB / TPB, 256, 0, stream>>>(x, emb, W, bU, xw);
    rnn_scan_mfma<<<BB / ROWS, 256, 0, stream>>>(xw, U, V, bV, out);
}

// Round 18
// 1082.578 us; speedup vs baseline: 1.1985x; 1.1985x over previous
//
#include <hip/hip_runtime.h>
#include <hip/hip_bf16.h>

// RNN_80848464380442: B=64, S=2048, V=50257, E=128, H=256, C=2 (f32 in/out, x int32)
// Stage 1: xw[tok][sig(j)] = bU[j] + sum_e emb[x]*W  (fp16 to ws, sigma-permuted cols)
// Stage 2: MFMA scan, 16 blocks x 4 batch rows, 8 waves x 2 N-tiles (512 thr, 2 w/SIMD).
//          4-dup rows in M=16: A-reads broadcast row n&3 (conflict-free), D slot q =
//          batch row q for every kg -> lane (n,kg) owns (row kg, 2 cols): 2 tanh +
//          1 pkrtz + 1 b32 write + 1 xw dword/step. xw folded into MFMA C.
//          2-step prefetch ring; plain __syncthreads (asm barriers regressed R10-12).
// Stage 3: logits + h output post-loop from LDS.
// sigma: j = 32w+16s+n  ->  p = 32w+2n+s

#define HB 256
#define EB 128
#define SB 2048
#define BB 64
#define TPB 32
#define ROWS 4
#define PITCH 264   // u16/row = 528 B; broadcast reads + 2-way max on writes (free)

typedef unsigned short u16;
typedef __attribute__((ext_vector_type(4))) float f32x4;
typedef __attribute__((ext_vector_type(8))) _Float16 f16x8;
typedef __attribute__((ext_vector_type(2))) __fp16 fp16x2_t;

__device__ __forceinline__ u16 f2h_bits(float f) {
    union { _Float16 h; u16 b; } x; x.h = (_Float16)f; return x.b;
}
__device__ __forceinline__ float h2f_bits(u16 b) {
    union { u16 b; _Float16 h; } x; x.b = b; return (float)x.h;
}
__device__ __forceinline__ float tanh_fast(float z) {
    float E = exp2f(z * 2.885390082f);             // e^(2z); tanh = 1 - 2/(e^2z + 1)
    return fmaf(-2.f, __builtin_amdgcn_rcpf(E + 1.f), 1.f);
}
__device__ __forceinline__ unsigned pkrtz(float a, float b) {
    fp16x2_t p = __builtin_amdgcn_cvt_pkrtz(a, b);
    return __builtin_bit_cast(unsigned, p);
}
__device__ __forceinline__ float sel4(f32x4 v, int kg) {   // v[kg] via cndmask chain
    float r = v[0];
    r = (kg == 1) ? v[1] : r;
    r = (kg == 2) ? v[2] : r;
    r = (kg == 3) ? v[3] : r;
    return r;
}

__device__ __forceinline__ int sig(int j)    { return (j & 0xE0) | ((j & 15) << 1) | ((j >> 4) & 1); }
__device__ __forceinline__ int invsig(int p) { return (p & 0xE0) | ((p & 1) << 4) | ((p >> 1) & 15); }

// ---------------- Stage 1: embed + project (32 tokens per 256-thread block) --------
__global__ __launch_bounds__(256) void embed_proj(
    const int* __restrict__ x, const float* __restrict__ emb,
    const float* __restrict__ W, const float* __restrict__ bU,
    u16* __restrict__ xw)
{
    __shared__ __align__(16) float el[TPB][EB];   // 16 KB
    __shared__ int toks[TPB];

    const int tid = threadIdx.x;
    const long base = (long)blockIdx.x * TPB;

    if (tid < TPB) toks[tid] = x[base + tid];
    __syncthreads();

    for (int r = 0; r < TPB * EB / 256; ++r) {
        int i = tid + r * 256;
        int row = i >> 7, e = i & (EB - 1);
        int u = toks[row];
        el[row][e] = (u == 0) ? 0.f : emb[(size_t)u * EB + e];   // padding_idx=0
    }
    __syncthreads();

    const int j = tid;
    const int sj = sig(j);
    const float bu = bU[j];
    float acc[TPB];
    #pragma unroll
    for (int t = 0; t < TPB; ++t) acc[t] = bu;

    for (int e0 = 0; e0 < EB; e0 += 4) {
        float w0 = W[(e0 + 0) * HB + j];
        float w1 = W[(e0 + 1) * HB + j];
        float w2 = W[(e0 + 2) * HB + j];
        float w3 = W[(e0 + 3) * HB + j];
        #pragma unroll
        for (int t = 0; t < TPB; ++t) {
            float4 ev = *(const float4*)&el[t][e0];
            acc[t] = fmaf(ev.x, w0, acc[t]);
            acc[t] = fmaf(ev.y, w1, acc[t]);
            acc[t] = fmaf(ev.z, w2, acc[t]);
            acc[t] = fmaf(ev.w, w3, acc[t]);
        }
    }
    #pragma unroll
    for (int t = 0; t < TPB; ++t)
        xw[(base + t) * HB + sj] = f2h_bits(acc[t]);
}

// ---------------- Stage 2+3: MFMA scan, 16 blocks x 512 threads (8 waves) ----------
// STEP(T, X): X = this lane's xw dword (row kg, 2 tile cols) for step T;
// C-init splats X into both accs (non-kg slots discarded), reissue X <- T+2,
// broadcast A-reads (row n&3), 16 MFMAs, 2 tanh, one b32 write, barrier.
#define STEP(T, X)                                                                 \
  {                                                                                \
    const int cb = (T) & 1, nb = cb ^ 1;                                           \
    float xv0 = h2f_bits((u16)(X & 0xffffu));                                      \
    float xv1 = h2f_bits((u16)(X >> 16));                                          \
    f32x4 acc0 = {xv0, xv0, xv0, xv0};                                             \
    f32x4 acc1 = {xv1, xv1, xv1, xv1};                                             \
    {                                                                              \
        const unsigned toff = (unsigned)(((T) + 2 < SB) ? (T) + 2 : SB - 1) * HB;  \
        X = *(const unsigned*)&xw[gb + toff];                                      \
    }                                                                              \
    f16x8 Af[8];                                                                   \
    _Pragma("unroll")                                                              \
    for (int ks = 0; ks < 8; ++ks) {                                               \
        uint4 av = *(const uint4*)&H[cb][n & 3][ks * 32 + kg * 8];                 \
        Af[ks] = __builtin_bit_cast(f16x8, av);                                    \
    }                                                                              \
    _Pragma("unroll")                                                              \
    for (int ks = 0; ks < 8; ++ks) {                                               \
        acc0 = __builtin_amdgcn_mfma_f32_16x16x32_f16(Af[ks], Bf[0][ks], acc0, 0, 0, 0); \
        acc1 = __builtin_amdgcn_mfma_f32_16x16x32_f16(Af[ks], Bf[1][ks], acc1, 0, 0, 0); \
    }                                                                              \
    {                                                                              \
        float t0 = tanh_fast(sel4(acc0, kg));                                      \
        float t1 = tanh_fast(sel4(acc1, kg));                                      \
        *(unsigned*)&H[nb][kg][pbase] = pkrtz(t0, t1);                             \
    }                                                                              \
    __syncthreads();                                                               \
  }

__global__ __launch_bounds__(512, 2) void rnn_scan_mfma(
    const u16* __restrict__ xw, const float* __restrict__ U,
    const float* __restrict__ V, const float* __restrict__ bV,
    float* __restrict__ out)
{
    __shared__ __align__(16) u16 H[2][ROWS][PITCH];   // double-buffered h (fp16), sigma order

    const int tid  = threadIdx.x;
    const int lane = tid & 63;
    const int w    = tid >> 6;            // wave 0..7, owns N-tiles 2w, 2w+1
    const int b0   = blockIdx.x * ROWS;

    {   // zero both H buffers (incl. pad)
        unsigned* hz = (unsigned*)H;
        for (int i = tid; i < 2 * ROWS * PITCH / 2; i += 512) hz[i] = 0u;
    }

    const int n  = lane & 15;             // A-m / B-n / D-col
    const int kg = lane >> 4;             // 0..3; lane owns batch row kg

    // ---- B-frag preload via sigma^-1: Bf[s][ks], tile nt=2w+s, col j_out=nt*16+n ----
    f16x8 Bf[2][8];
    #pragma unroll
    for (int s = 0; s < 2; ++s) {
        const int col = (2 * w + s) * 16 + n;
        #pragma unroll
        for (int ks = 0; ks < 8; ++ks) {
            union { f16x8 v; u16 h[8]; } tmp;
            #pragma unroll
            for (int e = 0; e < 8; ++e) {
                const int p = ks * 32 + kg * 8 + e;          // storage k
                const int jin = invsig(p);                   // actual contraction j
                tmp.h[e] = f2h_bits(U[(size_t)jin * HB + col]);
            }
            Bf[s][ks] = tmp.v;
        }
    }

    // ---- per-lane mapping: row kg, col pair (tiles 2w, 2w+1) at pbase = 32w+2n ----
    const int pbase = 32 * w + 2 * n;
    const unsigned gb = ((unsigned)(b0 + kg) * SB) * HB + pbase;
    unsigned XA = *(const unsigned*)&xw[gb];             // t = 0
    unsigned XB = *(const unsigned*)&xw[gb + HB];        // t = 1
    __syncthreads();

    for (int t = 0; t < SB; t += 2) {
        STEP(t,     XA);
        STEP(t + 1, XB);
    }

    // h output (f32 from fp16 H[0]; SB even -> final h in buffer 0)
    for (int i = tid; i < ROWS * HB; i += 512) {
        const int r = i >> 8, p = i & 255;
        out[BB * 2 + (size_t)(b0 + r) * HB + invsig(p)] = h2f_bits(H[0][r][p]);
    }

    // logits: first 64 threads = 4 rows x 16 partials
    if (tid < ROWS * 16) {
        const int r = tid >> 4, part = tid & 15;
        float s0 = 0.f, s1 = 0.f;
        #pragma unroll
        for (int i = 0; i < 16; ++i) {
            const int p = part * 16 + i;
            const int j = invsig(p);
            float hh = h2f_bits(H[0][r][p]);
            s0 = fmaf(hh, V[j * 2 + 0], s0);
            s1 = fmaf(hh, V[j * 2 + 1], s1);
        }
        #pragma unroll
        for (int o = 8; o > 0; o >>= 1) {
            s0 += __shfl_down(s0, o, 16);
            s1 += __shfl_down(s1, o, 16);
        }
        if (part == 0) {
            out[(size_t)(b0 + r) * 2 + 0] = s0 + bV[0];
            out[(size_t)(b0 + r) * 2 + 1] = s1 + bV[1];
        }
    }
}

extern "C" void kernel_launch(void* const* d_in, const int* in_sizes, int n_in,
                              void* d_out, int out_size, void* d_ws, size_t ws_size,
                              hipStream_t stream) {
    const int*   x   = (const int*)d_in[0];
    const float* emb = (const float*)d_in[1];
    const float* W   = (const float*)d_in[2];
    const float* U   = (const float*)d_in[3];
    const float* bU  = (const float*)d_in[4];
    const float* V   = (const float*)d_in[5];
    const float* bV  = (const float*)d_in[6];
    float* out = (float*)d_out;
    u16*   xw  = (u16*)d_ws;   // 64 MiB fp16 scratch, sigma-permuted columns

    embed_proj<<<BB * SB / TPB, 256, 0, stream>>>(x, emb, W, bU, xw);
    rnn_scan_mfma<<<BB / ROWS, 512, 0, stream>>>(xw, U, V, bV, out);
}

// Round 19
// 1064.826 us; speedup vs baseline: 1.2185x; 1.0167x over previous
//
#include <hip/hip_runtime.h>
#include <hip/hip_bf16.h>

// RNN_80848464380442: B=64, S=2048, V=50257, E=128, H=256, C=2 (f32 in/out, x int32)
// Stage 1: xw[tok][sig(j)] = bU[j] + sum_e emb[x]*W  (fp16 to ws, sigma-permuted cols)
// Stage 2: MFMA scan, 16 blocks x 4 batch rows, 8 waves x 2 N-tiles (512 thr, 2 w/SIMD).
//          4-dup rows in M=16: A-reads broadcast row n&3; PITCH=272 -> read start
//          group (2r+kg) mod 8 uniform 2-way (FREE; R18's 264 gave triangular 4-way,
//          8.9M conflicts). D slot q = batch row q -> lane (n,kg) owns (row kg,
//          2 cols): 2 tanh + 1 pkrtz + 1 b32 write + 1 xw dword/step. xw folded
//          into MFMA C. 2-step prefetch ring; plain __syncthreads.
// Stage 3: logits + h output post-loop from LDS.
// sigma: j = 32w+16s+n  ->  p = 32w+2n+s

#define HB 256
#define EB 128
#define SB 2048
#define BB 64
#define TPB 32
#define ROWS 4
#define PITCH 272   // u16/row = 544 B = 34 x 16B; 34 mod 8 = 2 -> uniform 2-way reads

typedef unsigned short u16;
typedef __attribute__((ext_vector_type(4))) float f32x4;
typedef __attribute__((ext_vector_type(8))) _Float16 f16x8;
typedef __attribute__((ext_vector_type(2))) __fp16 fp16x2_t;

__device__ __forceinline__ u16 f2h_bits(float f) {
    union { _Float16 h; u16 b; } x; x.h = (_Float16)f; return x.b;
}
__device__ __forceinline__ float h2f_bits(u16 b) {
    union { u16 b; _Float16 h; } x; x.b = b; return (float)x.h;
}
__device__ __forceinline__ float tanh_fast(float z) {
    float E = exp2f(z * 2.885390082f);             // e^(2z); tanh = 1 - 2/(e^2z + 1)
    return fmaf(-2.f, __builtin_amdgcn_rcpf(E + 1.f), 1.f);
}
__device__ __forceinline__ unsigned pkrtz(float a, float b) {
    fp16x2_t p = __builtin_amdgcn_cvt_pkrtz(a, b);
    return __builtin_bit_cast(unsigned, p);
}
__device__ __forceinline__ float sel4(f32x4 v, int kg) {   // v[kg] via cndmask chain
    float r = v[0];
    r = (kg == 1) ? v[1] : r;
    r = (kg == 2) ? v[2] : r;
    r = (kg == 3) ? v[3] : r;
    return r;
}

__device__ __forceinline__ int sig(int j)    { return (j & 0xE0) | ((j & 15) << 1) | ((j >> 4) & 1); }
__device__ __forceinline__ int invsig(int p) { return (p & 0xE0) | ((p & 1) << 4) | ((p >> 1) & 15); }

// ---------------- Stage 1: embed + project (32 tokens per 256-thread block) --------
__global__ __launch_bounds__(256) void embed_proj(
    const int* __restrict__ x, const float* __restrict__ emb,
    const float* __restrict__ W, const float* __restrict__ bU,
    u16* __restrict__ xw)
{
    __shared__ __align__(16) float el[TPB][EB];   // 16 KB
    __shared__ int toks[TPB];

    const int tid = threadIdx.x;
    const long base = (long)blockIdx.x * TPB;

    if (tid < TPB) toks[tid] = x[base + tid];
    __syncthreads();

    for (int r = 0; r < TPB * EB / 256; ++r) {
        int i = tid + r * 256;
        int row = i >> 7, e = i & (EB - 1);
        int u = toks[row];
        el[row][e] = (u == 0) ? 0.f : emb[(size_t)u * EB + e];   // padding_idx=0
    }
    __syncthreads();

    const int j = tid;
    const int sj = sig(j);
    const float bu = bU[j];
    float acc[TPB];
    #pragma unroll
    for (int t = 0; t < TPB; ++t) acc[t] = bu;

    for (int e0 = 0; e0 < EB; e0 += 4) {
        float w0 = W[(e0 + 0) * HB + j];
        float w1 = W[(e0 + 1) * HB + j];
        float w2 = W[(e0 + 2) * HB + j];
        float w3 = W[(e0 + 3) * HB + j];
        #pragma unroll
        for (int t = 0; t < TPB; ++t) {
            float4 ev = *(const float4*)&el[t][e0];
            acc[t] = fmaf(ev.x, w0, acc[t]);
            acc[t] = fmaf(ev.y, w1, acc[t]);
            acc[t] = fmaf(ev.z, w2, acc[t]);
            acc[t] = fmaf(ev.w, w3, acc[t]);
        }
    }
    #pragma unroll
    for (int t = 0; t < TPB; ++t)
        xw[(base + t) * HB + sj] = f2h_bits(acc[t]);
}

// ---------------- Stage 2+3: MFMA scan, 16 blocks x 512 threads (8 waves) ----------
// STEP(T, X): X = this lane's xw dword (row kg, 2 tile cols) for step T;
// C-init splats X into both accs (non-kg slots discarded), reissue X <- T+2,
// broadcast A-reads (row n&3), 16 MFMAs, 2 tanh, one b32 write, barrier.
#define STEP(T, X)                                                                 \
  {                                                                                \
    const int cb = (T) & 1, nb = cb ^ 1;                                           \
    float xv0 = h2f_bits((u16)(X & 0xffffu));                                      \
    float xv1 = h2f_bits((u16)(X >> 16));                                          \
    f32x4 acc0 = {xv0, xv0, xv0, xv0};                                             \
    f32x4 acc1 = {xv1, xv1, xv1, xv1};                                             \
    {                                                                              \
        const unsigned toff = (unsigned)(((T) + 2 < SB) ? (T) + 2 : SB - 1) * HB;  \
        X = *(const unsigned*)&xw[gb + toff];                                      \
    }                                                                              \
    f16x8 Af[8];                                                                   \
    _Pragma("unroll")                                                              \
    for (int ks = 0; ks < 8; ++ks) {                                               \
        uint4 av = *(const uint4*)&H[cb][n & 3][ks * 32 + kg * 8];                 \
        Af[ks] = __builtin_bit_cast(f16x8, av);                                    \
    }                                                                              \
    _Pragma("unroll")                                                              \
    for (int ks = 0; ks < 8; ++ks) {                                               \
        acc0 = __builtin_amdgcn_mfma_f32_16x16x32_f16(Af[ks], Bf[0][ks], acc0, 0, 0, 0); \
        acc1 = __builtin_amdgcn_mfma_f32_16x16x32_f16(Af[ks], Bf[1][ks], acc1, 0, 0, 0); \
    }                                                                              \
    {                                                                              \
        float t0 = tanh_fast(sel4(acc0, kg));                                      \
        float t1 = tanh_fast(sel4(acc1, kg));                                      \
        *(unsigned*)&H[nb][kg][pbase] = pkrtz(t0, t1);                             \
    }                                                                              \
    __syncthreads();                                                               \
  }

__global__ __launch_bounds__(512, 2) void rnn_scan_mfma(
    const u16* __restrict__ xw, const float* __restrict__ U,
    const float* __restrict__ V, const float* __restrict__ bV,
    float* __restrict__ out)
{
    __shared__ __align__(16) u16 H[2][ROWS][PITCH];   // double-buffered h (fp16), sigma order

    const int tid  = threadIdx.x;
    const int lane = tid & 63;
    const int w    = tid >> 6;            // wave 0..7, owns N-tiles 2w, 2w+1
    const int b0   = blockIdx.x * ROWS;

    {   // zero both H buffers (incl. pad)
        unsigned* hz = (unsigned*)H;
        for (int i = tid; i < 2 * ROWS * PITCH / 2; i += 512) hz[i] = 0u;
    }

    const int n  = lane & 15;             // A-m / B-n / D-col
    const int kg = lane >> 4;             // 0..3; lane owns batch row kg

    // ---- B-frag preload via sigma^-1: Bf[s][ks], tile nt=2w+s, col j_out=nt*16+n ----
    f16x8 Bf[2][8];
    #pragma unroll
    for (int s = 0; s < 2; ++s) {
        const int col = (2 * w + s) * 16 + n;
        #pragma unroll
        for (int ks = 0; ks < 8; ++ks) {
            union { f16x8 v; u16 h[8]; } tmp;
            #pragma unroll
            for (int e = 0; e < 8; ++e) {
                const int p = ks * 32 + kg * 8 + e;          // storage k
                const int jin = invsig(p);                   // actual contraction j
                tmp.h[e] = f2h_bits(U[(size_t)jin * HB + col]);
            }
            Bf[s][ks] = tmp.v;
        }
    }

    // ---- per-lane mapping: row kg, col pair (tiles 2w, 2w+1) at pbase = 32w+2n ----
    const int pbase = 32 * w + 2 * n;
    const unsigned gb = ((unsigned)(b0 + kg) * SB) * HB + pbase;
    unsigned XA = *(const unsigned*)&xw[gb];             // t = 0
    unsigned XB = *(const unsigned*)&xw[gb + HB];        // t = 1
    __syncthreads();

    for (int t = 0; t < SB; t += 2) {
        STEP(t,     XA);
        STEP(t + 1, XB);
    }

    // h output (f32 from fp16 H[0]; SB even -> final h in buffer 0)
    for (int i = tid; i < ROWS * HB; i += 512) {
        const int r = i >> 8, p = i & 255;
        out[BB * 2 + (size_t)(b0 + r) * HB + invsig(p)] = h2f_bits(H[0][r][p]);
    }

    // logits: first 64 threads = 4 rows x 16 partials
    if (tid < ROWS * 16) {
        const int r = tid >> 4, part = tid & 15;
        float s0 = 0.f, s1 = 0.f;
        #pragma unroll
        for (int i = 0; i < 16; ++i) {
            const int p = part * 16 + i;
            const int j = invsig(p);
            float hh = h2f_bits(H[0][r][p]);
            s0 = fmaf(hh, V[j * 2 + 0], s0);
            s1 = fmaf(hh, V[j * 2 + 1], s1);
        }
        #pragma unroll
        for (int o = 8; o > 0; o >>= 1) {
            s0 += __shfl_down(s0, o, 16);
            s1 += __shfl_down(s1, o, 16);
        }
        if (part == 0) {
            out[(size_t)(b0 + r) * 2 + 0] = s0 + bV[0];
            out[(size_t)(b0 + r) * 2 + 1] = s1 + bV[1];
        }
    }
}

extern "C" void kernel_launch(void* const* d_in, const int* in_sizes, int n_in,
                              void* d_out, int out_size, void* d_ws, size_t ws_size,
                              hipStream_t stream) {
    const int*   x   = (const int*)d_in[0];
    const float* emb = (const float*)d_in[1];
    const float* W   = (const float*)d_in[2];
    const float* U   = (const float*)d_in[3];
    const float* bU  = (const float*)d_in[4];
    const float* V   = (const float*)d_in[5];
    const float* bV  = (const float*)d_in[6];
    float* out = (float*)d_out;
    u16*   xw  = (u16*)d_ws;   // 64 MiB fp16 scratch, sigma-permuted columns

    embed_proj<<<BB * SB / TPB, 256, 0, stream>>>(x, emb, W, bU, xw);
    rnn_scan_mfma<<<BB / ROWS, 512, 0, stream>>>(xw, U, V, bV, out);
}

// Round 20
// 942.964 us; speedup vs baseline: 1.3759x; 1.1292x over previous
//
#include <hip/hip_runtime.h>
#include <hip/hip_bf16.h>

// RNN_80848464380442: B=64, S=2048, V=50257, E=128, H=256, C=2 (f32 in/out, x int32)
// Stage 1: MFMA embed+project: (64 tokens/block) x (128x256 W), fp16 MFMA, bU in C-init,
//          sigma applied at xw write (pairs s=0,1 / s=2,3 -> dword stores).
// Stage 2: MFMA scan (R19, at structural floor): 16 blocks x 4 batch rows, 8 waves x
//          2 N-tiles (512 thr, 2 w/SIMD), 4-dup rows, PITCH=272 uniform banks,
//          lane (n,kg) owns (row kg, 2 cols), xw in MFMA C, 2-step prefetch ring.
// Stage 3: logits + h output post-loop from LDS.
// sigma: j = 32w+16s+n  ->  p = 32w+2n+s

#define HB 256
#define EB 128
#define SB 2048
#define BB 64
#define ETPB 64     // tokens per embed block
#define APITCH 68   // u32 per el row = 136 u16 = 17 x 16B (odd) -> uniform LDS banks
#define ROWS 4
#define PITCH 272   // u16/row = 544 B = 34 x 16B; 34 mod 8 = 2 -> uniform 2-way reads

typedef unsigned short u16;
typedef __attribute__((ext_vector_type(4))) float f32x4;
typedef __attribute__((ext_vector_type(8))) _Float16 f16x8;
typedef __attribute__((ext_vector_type(2))) __fp16 fp16x2_t;

__device__ __forceinline__ u16 f2h_bits(float f) {
    union { _Float16 h; u16 b; } x; x.h = (_Float16)f; return x.b;
}
__device__ __forceinline__ float h2f_bits(u16 b) {
    union { u16 b; _Float16 h; } x; x.b = b; return (float)x.h;
}
__device__ __forceinline__ float tanh_fast(float z) {
    float E = exp2f(z * 2.885390082f);             // e^(2z); tanh = 1 - 2/(e^2z + 1)
    return fmaf(-2.f, __builtin_amdgcn_rcpf(E + 1.f), 1.f);
}
__device__ __forceinline__ unsigned pkrtz(float a, float b) {
    fp16x2_t p = __builtin_amdgcn_cvt_pkrtz(a, b);
    return __builtin_bit_cast(unsigned, p);
}
__device__ __forceinline__ unsigned pkrne(float a, float b) {   // RNE fp16 pair
    return (unsigned)f2h_bits(a) | ((unsigned)f2h_bits(b) << 16);
}
__device__ __forceinline__ float sel4(f32x4 v, int kg) {   // v[kg] via cndmask chain
    float r = v[0];
    r = (kg == 1) ? v[1] : r;
    r = (kg == 2) ? v[2] : r;
    r = (kg == 3) ? v[3] : r;
    return r;
}

__device__ __forceinline__ int sig(int j)    { return (j & 0xE0) | ((j & 15) << 1) | ((j >> 4) & 1); }
__device__ __forceinline__ int invsig(int p) { return (p & 0xE0) | ((p & 1) << 4) | ((p >> 1) & 15); }

// ---------------- Stage 1: MFMA embed + project (64 tokens per 256-thread block) ---
__global__ __launch_bounds__(256) void embed_proj_mfma(
    const int* __restrict__ x, const float* __restrict__ emb,
    const float* __restrict__ W, const float* __restrict__ bU,
    u16* __restrict__ xw)
{
    __shared__ int toks[ETPB];
    __shared__ __align__(16) unsigned el[ETPB * APITCH];   // fp16 pairs, 17.4 KB

    const int tid = threadIdx.x;
    const long base = (long)blockIdx.x * ETPB;
    if (tid < ETPB) toks[tid] = x[base + tid];
    __syncthreads();

    // stage emb rows as fp16 pairs: 64 rows x 64 u32, 16 per thread (float2 coalesced)
    #pragma unroll
    for (int r = 0; r < ETPB * 64 / 256; ++r) {
        int idx = tid + r * 256;
        int row = idx >> 6, ep = idx & 63;
        int u = toks[row];
        unsigned pk = 0u;                                  // padding_idx = 0
        if (u != 0) {
            float2 v = *(const float2*)&emb[(size_t)u * EB + 2 * ep];
            pk = pkrne(v.x, v.y);
        }
        el[row * APITCH + ep] = pk;
    }

    const int lane = tid & 63;
    const int w    = tid >> 6;            // wave 0..3, owns col-tiles 4w..4w+3
    const int n    = lane & 15;
    const int kg   = lane >> 4;

    // B-frags (W, natural k) + bU per owned column
    f16x8 Bf[4][4];
    float bu[4];
    #pragma unroll
    for (int s = 0; s < 4; ++s) {
        const int col = (4 * w + s) * 16 + n;
        bu[s] = bU[col];
        #pragma unroll
        for (int ks = 0; ks < 4; ++ks) {
            union { f16x8 v; u16 h[8]; } tmp;
            #pragma unroll
            for (int e = 0; e < 8; ++e)
                tmp.h[e] = f2h_bits(W[(size_t)(ks * 32 + kg * 8 + e) * HB + col]);
            Bf[s][ks] = tmp.v;
        }
    }
    __syncthreads();

    #pragma unroll
    for (int mt = 0; mt < 4; ++mt) {
        f16x8 Af[4];
        #pragma unroll
        for (int ks = 0; ks < 4; ++ks) {
            uint4 av = *(const uint4*)&el[(mt * 16 + n) * APITCH + ks * 16 + kg * 4];
            Af[ks] = __builtin_bit_cast(f16x8, av);
        }
        f32x4 acc0 = {bu[0], bu[0], bu[0], bu[0]};
        f32x4 acc1 = {bu[1], bu[1], bu[1], bu[1]};
        f32x4 acc2 = {bu[2], bu[2], bu[2], bu[2]};
        f32x4 acc3 = {bu[3], bu[3], bu[3], bu[3]};
        #pragma unroll
        for (int ks = 0; ks < 4; ++ks) {
            acc0 = __builtin_amdgcn_mfma_f32_16x16x32_f16(Af[ks], Bf[0][ks], acc0, 0, 0, 0);
            acc1 = __builtin_amdgcn_mfma_f32_16x16x32_f16(Af[ks], Bf[1][ks], acc1, 0, 0, 0);
            acc2 = __builtin_amdgcn_mfma_f32_16x16x32_f16(Af[ks], Bf[2][ks], acc2, 0, 0, 0);
            acc3 = __builtin_amdgcn_mfma_f32_16x16x32_f16(Af[ks], Bf[3][ks], acc3, 0, 0, 0);
        }
        // sigma write: cols (4w+s)*16+n; s=0,1 -> p = 64w+2n+{0,1}; s=2,3 -> +32
        #pragma unroll
        for (int q = 0; q < 4; ++q) {
            const long tok = base + mt * 16 + kg * 4 + q;
            *(unsigned*)&xw[tok * HB + 64 * w + 2 * n]      = pkrne(acc0[q], acc1[q]);
            *(unsigned*)&xw[tok * HB + 64 * w + 32 + 2 * n] = pkrne(acc2[q], acc3[q]);
        }
    }
}

// ---------------- Stage 2+3: MFMA scan, 16 blocks x 512 threads (8 waves) ----------
// STEP(T, X): X = this lane's xw dword (row kg, 2 tile cols) for step T;
// C-init splats X into both accs (non-kg slots discarded), reissue X <- T+2,
// broadcast A-reads (row n&3), 16 MFMAs, 2 tanh, one b32 write, barrier.
#define STEP(T, X)                                                                 \
  {                                                                                \
    const int cb = (T) & 1, nb = cb ^ 1;                                           \
    float xv0 = h2f_bits((u16)(X & 0xffffu));                                      \
    float xv1 = h2f_bits((u16)(X >> 16));                                          \
    f32x4 acc0 = {xv0, xv0, xv0, xv0};                                             \
    f32x4 acc1 = {xv1, xv1, xv1, xv1};                                             \
    {                                                                              \
        const unsigned toff = (unsigned)(((T) + 2 < SB) ? (T) + 2 : SB - 1) * HB;  \
        X = *(const unsigned*)&xw[gb + toff];                                      \
    }                                                                              \
    f16x8 Af[8];                                                                   \
    _Pragma("unroll")                                                              \
    for (int ks = 0; ks < 8; ++ks) {                                               \
        uint4 av = *(const uint4*)&H[cb][n & 3][ks * 32 + kg * 8];                 \
        Af[ks] = __builtin_bit_cast(f16x8, av);                                    \
    }                                                                              \
    _Pragma("unroll")                                                              \
    for (int ks = 0; ks < 8; ++ks) {                                               \
        acc0 = __builtin_amdgcn_mfma_f32_16x16x32_f16(Af[ks], Bf[0][ks], acc0, 0, 0, 0); \
        acc1 = __builtin_amdgcn_mfma_f32_16x16x32_f16(Af[ks], Bf[1][ks], acc1, 0, 0, 0); \
    }                                                                              \
    {                                                                              \
        float t0 = tanh_fast(sel4(acc0, kg));                                      \
        float t1 = tanh_fast(sel4(acc1, kg));                                      \
        *(unsigned*)&H[nb][kg][pbase] = pkrtz(t0, t1);                             \
    }                                                                              \
    __syncthreads();                                                               \
  }

__global__ __launch_bounds__(512, 2) void rnn_scan_mfma(
    const u16* __restrict__ xw, const float* __restrict__ U,
    const float* __restrict__ V, const float* __restrict__ bV,
    float* __restrict__ out)
{
    __shared__ __align__(16) u16 H[2][ROWS][PITCH];   // double-buffered h (fp16), sigma order

    const int tid  = threadIdx.x;
    const int lane = tid & 63;
    const int w    = tid >> 6;            // wave 0..7, owns N-tiles 2w, 2w+1
    const int b0   = blockIdx.x * ROWS;

    {   // zero both H buffers (incl. pad)
        unsigned* hz = (unsigned*)H;
        for (int i = tid; i < 2 * ROWS * PITCH / 2; i += 512) hz[i] = 0u;
    }

    const int n  = lane & 15;             // A-m / B-n / D-col
    const int kg = lane >> 4;             // 0..3; lane owns batch row kg

    // ---- B-frag preload via sigma^-1: Bf[s][ks], tile nt=2w+s, col j_out=nt*16+n ----
    f16x8 Bf[2][8];
    #pragma unroll
    for (int s = 0; s < 2; ++s) {
        const int col = (2 * w + s) * 16 + n;
        #pragma unroll
        for (int ks = 0; ks < 8; ++ks) {
            union { f16x8 v; u16 h[8]; } tmp;
            #pragma unroll
            for (int e = 0; e < 8; ++e) {
                const int p = ks * 32 + kg * 8 + e;          // storage k
                const int jin = invsig(p);                   // actual contraction j
                tmp.h[e] = f2h_bits(U[(size_t)jin * HB + col]);
            }
            Bf[s][ks] = tmp.v;
        }
    }

    // ---- per-lane mapping: row kg, col pair (tiles 2w, 2w+1) at pbase = 32w+2n ----
    const int pbase = 32 * w + 2 * n;
    const unsigned gb = ((unsigned)(b0 + kg) * SB) * HB + pbase;
    unsigned XA = *(const unsigned*)&xw[gb];             // t = 0
    unsigned XB = *(const unsigned*)&xw[gb + HB];        // t = 1
    __syncthreads();

    for (int t = 0; t < SB; t += 2) {
        STEP(t,     XA);
        STEP(t + 1, XB);
    }

    // h output (f32 from fp16 H[0]; SB even -> final h in buffer 0)
    for (int i = tid; i < ROWS * HB; i += 512) {
        const int r = i >> 8, p = i & 255;
        out[BB * 2 + (size_t)(b0 + r) * HB + invsig(p)] = h2f_bits(H[0][r][p]);
    }

    // logits: first 64 threads = 4 rows x 16 partials
    if (tid < ROWS * 16) {
        const int r = tid >> 4, part = tid & 15;
        float s0 = 0.f, s1 = 0.f;
        #pragma unroll
        for (int i = 0; i < 16; ++i) {
            const int p = part * 16 + i;
            const int j = invsig(p);
            float hh = h2f_bits(H[0][r][p]);
            s0 = fmaf(hh, V[j * 2 + 0], s0);
            s1 = fmaf(hh, V[j * 2 + 1], s1);
        }
        #pragma unroll
        for (int o = 8; o > 0; o >>= 1) {
            s0 += __shfl_down(s0, o, 16);
            s1 += __shfl_down(s1, o, 16);
        }
        if (part == 0) {
            out[(size_t)(b0 + r) * 2 + 0] = s0 + bV[0];
            out[(size_t)(b0 + r) * 2 + 1] = s1 + bV[1];
        }
    }
}

extern "C" void kernel_launch(void* const* d_in, const int* in_sizes, int n_in,
                              void* d_out, int out_size, void* d_ws, size_t ws_size,
                              hipStream_t stream) {
    const int*   x   = (const int*)d_in[0];
    const float* emb = (const float*)d_in[1];
    const float* W   = (const float*)d_in[2];
    const float* U   = (const float*)d_in[3];
    const float* bU  = (const float*)d_in[4];
    const float* V   = (const float*)d_in[5];
    const float* bV  = (const float*)d_in[6];
    float* out = (float*)d_out;
    u16*   xw  = (u16*)d_ws;   // 64 MiB fp16 scratch, sigma-permuted columns

    embed_proj_mfma<<<BB * SB / ETPB, 256, 0, stream>>>(x, emb, W, bU, xw);
    rnn_scan_mfma<<<BB / ROWS, 512, 0, stream>>>(xw, U, V, bV, out);
}